// Round 1
// baseline (422.066 us; speedup 1.0000x reference)
//
#include <hip/hip_runtime.h>

#define NODES 8192
#define H1 256
#define EMB 64
#define IN_SIZE (NODES + EMB)   // 8256
#define HID3 128

// ws layout (floats)
#define X_OFF    0                       // 8192
#define M_OFF    (X_OFF + NODES)         // 8192*64
#define PART_OFF (M_OFF + NODES*EMB)     // 256*64
#define LS_OFF   (PART_OFF + 256*EMB)    // 64
#define Y1_OFF   (LS_OFF + EMB)          // 256
#define Y3_OFF   (Y1_OFF + H1)           // 128

__device__ __forceinline__ float waveReduceSum(float v) {
    #pragma unroll
    for (int off = 32; off > 0; off >>= 1) v += __shfl_down(v, off, 64);
    return v;
}

// K1: x[i] = state[i][i]
__global__ __launch_bounds__(256) void k_diag(const float* __restrict__ state,
                                              float* __restrict__ x) {
    int i = blockIdx.x * 256 + threadIdx.x;
    x[i] = state[(size_t)i * NODES + i];
}

// K2: per row i:  s = dot(state[i,:], x) - x[i]^2  (adj excludes diagonal)
//     h1[j] = relu(s*w1[j]+b1[j]);  M[i][k] = sum_j h1[j]*w2[j*64+k]
__global__ __launch_bounds__(256) void k_row(const float* __restrict__ state,
                                             const float* __restrict__ x,
                                             const float* __restrict__ w1,
                                             const float* __restrict__ b1,
                                             const float* __restrict__ w2,
                                             float* __restrict__ M) {
    __shared__ float red[4];
    __shared__ float s_bcast;
    __shared__ float h1[H1];
    __shared__ float mp[4][EMB];

    const int i = blockIdx.x;
    const int tid = threadIdx.x;
    const float4* row4 = (const float4*)(state + (size_t)i * NODES);
    const float4* x4   = (const float4*)x;

    float acc = 0.f;
    #pragma unroll
    for (int it = 0; it < NODES / 4 / 256; ++it) {   // 8 iterations
        int j = tid + it * 256;
        float4 r = row4[j];
        float4 xv = x4[j];
        acc += r.x * xv.x + r.y * xv.y + r.z * xv.z + r.w * xv.w;
    }
    acc = waveReduceSum(acc);
    if ((tid & 63) == 0) red[tid >> 6] = acc;
    __syncthreads();
    if (tid == 0) {
        float s = red[0] + red[1] + red[2] + red[3];
        float xi = x[i];
        s_bcast = s - xi * xi;
    }
    __syncthreads();
    const float s = s_bcast;

    h1[tid] = fmaxf(s * w1[tid] + b1[tid], 0.f);
    __syncthreads();

    const int k = tid & 63, g = tid >> 6;
    float m = 0.f;
    #pragma unroll
    for (int jj = 0; jj < 64; ++jj) {
        int j = g * 64 + jj;
        m += h1[j] * w2[j * EMB + k];
    }
    mp[g][k] = m;
    __syncthreads();
    if (tid < EMB)
        M[(size_t)i * EMB + tid] = mp[0][tid] + mp[1][tid] + mp[2][tid] + mp[3][tid];
}

// K3: partial[b][k] = sum over 32 rows of adj[start][i] * M[i][k]
__global__ __launch_bounds__(256) void k_colpart(const float* __restrict__ state,
                                                 const int* __restrict__ pstart,
                                                 const float* __restrict__ M,
                                                 float* __restrict__ part) {
    __shared__ float mp[4][EMB];
    const int start = *pstart;
    const int b = blockIdx.x;
    const int t = threadIdx.x;
    const int k = t & 63, g = t >> 6;
    const float* srow = state + (size_t)start * NODES;
    float acc = 0.f;
    #pragma unroll
    for (int r = 0; r < 8; ++r) {
        int i = b * 32 + g + r * 4;
        float coef = (i == start) ? 0.f : srow[i];
        acc += coef * M[(size_t)i * EMB + k];
    }
    mp[g][k] = acc;
    __syncthreads();
    if (t < EMB) part[b * EMB + t] = mp[0][t] + mp[1][t] + mp[2][t] + mp[3][t];
}

// K4: reduce partials, + gc2_b, relu, log_softmax -> ls[64]
__global__ __launch_bounds__(256) void k_softmax(const float* __restrict__ part,
                                                 const float* __restrict__ b2,
                                                 float* __restrict__ ls) {
    __shared__ float mp[4][EMB];
    const int t = threadIdx.x;
    const int k = t & 63, g = t >> 6;
    float acc = 0.f;
    #pragma unroll
    for (int c = 0; c < 64; ++c) acc += part[(g * 64 + c) * EMB + k];
    mp[g][k] = acc;
    __syncthreads();
    if (t < 64) {  // first wave only
        float v = mp[0][k] + mp[1][k] + mp[2][k] + mp[3][k];
        v = fmaxf(v + b2[k], 0.f);
        float mx = v;
        #pragma unroll
        for (int off = 32; off; off >>= 1) mx = fmaxf(mx, __shfl_xor(mx, off, 64));
        float e = expf(v - mx);
        float se = e;
        #pragma unroll
        for (int off = 32; off; off >>= 1) se += __shfl_xor(se, off, 64);
        ls[k] = (v - mx) - logf(se);
    }
}

// K5: y1[o] = relu(dot(e, fc1_w[o,:]) + b[o]);  e = [state[start,:], ls]
__global__ __launch_bounds__(256) void k_fc1(const float* __restrict__ state,
                                             const int* __restrict__ pstart,
                                             const float* __restrict__ ls,
                                             const float* __restrict__ w,
                                             const float* __restrict__ b,
                                             float* __restrict__ y1) {
    __shared__ float red[4];
    const int o = blockIdx.x;
    const int t = threadIdx.x;
    const int start = *pstart;
    const float4* e4 = (const float4*)(state + (size_t)start * NODES);
    const float4* w4 = (const float4*)(w + (size_t)o * IN_SIZE);
    float acc = 0.f;
    #pragma unroll
    for (int it = 0; it < 8; ++it) {
        int j = t + it * 256;
        float4 a = e4[j], ww = w4[j];
        acc += a.x * ww.x + a.y * ww.y + a.z * ww.z + a.w * ww.w;
    }
    if (t < 64) acc += ls[t] * w[(size_t)o * IN_SIZE + NODES + t];
    acc = waveReduceSum(acc);
    if ((t & 63) == 0) red[t >> 6] = acc;
    __syncthreads();
    if (t == 0) y1[o] = fmaxf(red[0] + red[1] + red[2] + red[3] + b[o], 0.f);
}

// K6: y2 = relu(fc2_w @ y1 + b2); y3 = relu(fc3_w @ y2 + b3)   (one block)
__global__ __launch_bounds__(256) void k_fc23(const float* __restrict__ y1,
                                              const float* __restrict__ w2_,
                                              const float* __restrict__ b2_,
                                              const float* __restrict__ w3_,
                                              const float* __restrict__ b3_,
                                              float* __restrict__ y3) {
    __shared__ float ly[H1];
    __shared__ float ly2[H1];
    const int t = threadIdx.x;
    ly[t] = y1[t];
    __syncthreads();
    const float4* w4 = (const float4*)(w2_ + (size_t)t * H1);
    float acc = 0.f;
    #pragma unroll
    for (int j = 0; j < 64; ++j) {
        float4 ww = w4[j];
        acc += ww.x * ly[j*4] + ww.y * ly[j*4+1] + ww.z * ly[j*4+2] + ww.w * ly[j*4+3];
    }
    ly2[t] = fmaxf(acc + b2_[t], 0.f);
    __syncthreads();
    if (t < HID3) {
        const float4* w43 = (const float4*)(w3_ + (size_t)t * H1);
        float a3 = 0.f;
        #pragma unroll
        for (int j = 0; j < 64; ++j) {
            float4 ww = w43[j];
            a3 += ww.x * ly2[j*4] + ww.y * ly2[j*4+1] + ww.z * ly2[j*4+2] + ww.w * ly2[j*4+3];
        }
        y3[t] = fmaxf(a3 + b3_[t], 0.f);
    }
}

// K7: out[o] = relu(dot(y3, fc4_w[o,:]) + b[o]); one wave per output
__global__ __launch_bounds__(256) void k_fc4(const float* __restrict__ y3,
                                             const float* __restrict__ w,
                                             const float* __restrict__ b,
                                             float* __restrict__ out) {
    __shared__ float ly[HID3];
    const int t = threadIdx.x;
    if (t < HID3) ly[t] = y3[t];
    __syncthreads();
    const int wave = t >> 6, lane = t & 63;
    const int o = blockIdx.x * 4 + wave;
    const float* wr = w + (size_t)o * HID3;
    float acc = wr[lane] * ly[lane] + wr[64 + lane] * ly[64 + lane];
    acc = waveReduceSum(acc);
    if (lane == 0) out[o] = fmaxf(acc + b[o], 0.f);
}

extern "C" void kernel_launch(void* const* d_in, const int* in_sizes, int n_in,
                              void* d_out, int out_size, void* d_ws, size_t ws_size,
                              hipStream_t stream) {
    const float* state = (const float*)d_in[0];
    const int*   pstart= (const int*)  d_in[1];
    const float* gc1_w = (const float*)d_in[2];
    const float* gc1_b = (const float*)d_in[3];
    const float* gc2_w = (const float*)d_in[4];
    const float* gc2_b = (const float*)d_in[5];
    const float* fc1_w = (const float*)d_in[6];
    const float* fc1_b = (const float*)d_in[7];
    const float* fc2_w = (const float*)d_in[8];
    const float* fc2_b = (const float*)d_in[9];
    const float* fc3_w = (const float*)d_in[10];
    const float* fc3_b = (const float*)d_in[11];
    const float* fc4_w = (const float*)d_in[12];
    const float* fc4_b = (const float*)d_in[13];
    float* ws = (float*)d_ws;
    float* x    = ws + X_OFF;
    float* M    = ws + M_OFF;
    float* part = ws + PART_OFF;
    float* ls   = ws + LS_OFF;
    float* y1   = ws + Y1_OFF;
    float* y3   = ws + Y3_OFF;
    float* out  = (float*)d_out;

    k_diag   <<<NODES / 256, 256, 0, stream>>>(state, x);
    k_row    <<<NODES,       256, 0, stream>>>(state, x, gc1_w, gc1_b, gc2_w, M);
    k_colpart<<<256,         256, 0, stream>>>(state, pstart, M, part);
    k_softmax<<<1,           256, 0, stream>>>(part, gc2_b, ls);
    k_fc1    <<<H1,          256, 0, stream>>>(state, pstart, ls, fc1_w, fc1_b, y1);
    k_fc23   <<<1,           256, 0, stream>>>(y1, fc2_w, fc2_b, fc3_w, fc3_b, y3);
    k_fc4    <<<8192 / 4,    256, 0, stream>>>(y3, fc4_w, fc4_b, out);
}